// Round 6
// baseline (644.562 us; speedup 1.0000x reference)
//
#include <hip/hip_runtime.h>
#include <cstdint>
#include <cmath>

#define B_ 2
#define S_ 2048
#define D_ 2048
#define H_ 16
#define HD_ 128

#define NEG_SENTINEL -1.0e30f

typedef __bf16 bf16;
typedef __attribute__((ext_vector_type(4))) __bf16 bf16x4;
typedef __attribute__((ext_vector_type(8))) __bf16 bf16x8;
typedef __attribute__((ext_vector_type(4))) float f32x4;

__device__ __forceinline__ void gload_lds16(const void* g, void* l) {
  __builtin_amdgcn_global_load_lds(
      (const __attribute__((address_space(1))) unsigned int*)g,
      (__attribute__((address_space(3))) unsigned int*)l, 16, 0, 0);
}

__device__ __forceinline__ f32x4 mfma16(bf16x8 a, bf16x8 b, f32x4 c) {
  return __builtin_amdgcn_mfma_f32_16x16x32_bf16(a, b, c, 0, 0, 0);
}

// ---------------------------------------------------------------------------
// fp32 -> bf16 convert. One thread = 4 elements.
// ---------------------------------------------------------------------------
__global__ __launch_bounds__(256) void cvt_f32_bf16(
    const float* __restrict__ in, bf16* __restrict__ out)
{
  int i = blockIdx.x * 256 + threadIdx.x;
  f32x4 v = ((const f32x4*)in)[i];
  bf16x4 o;
#pragma unroll
  for (int j = 0; j < 4; ++j) o[j] = (bf16)v[j];
  ((bf16x4*)out)[i] = o;
}

// ---------------------------------------------------------------------------
// GEMM: C[m][n] = sum_k A[m][k] * W[n][k], bf16 in, fp32 acc, OT out.
// 128x128 tile, BK=64, XOR chunk swizzle. (verified round 3)
// ---------------------------------------------------------------------------
#define GTM 128
#define GTN 128
#define GBK 64

template <typename OT>
__global__ __launch_bounds__(256) void gemm_xwt(
    const bf16* __restrict__ A, const bf16* __restrict__ W, OT* __restrict__ C,
    int M, int N, int K)
{
  __shared__ bf16 sA[GTM * GBK];
  __shared__ bf16 sB[GTN * GBK];
  const int tid  = threadIdx.x;
  const int wave = tid >> 6, lane = tid & 63;
  const int quad = lane >> 4, l16 = lane & 15;
  const int tm = blockIdx.y * GTM;
  const int tn = blockIdx.x * GTN;
  const int wm = (wave >> 1) * 64, wn = (wave & 1) * 64;

  f32x4 acc[4][4];
#pragma unroll
  for (int i = 0; i < 4; ++i)
#pragma unroll
    for (int j = 0; j < 4; ++j) acc[i][j] = (f32x4)0.0f;

  for (int k0 = 0; k0 < K; k0 += GBK) {
    __syncthreads();
#pragma unroll
    for (int g = 0; g < 4; ++g) {
      int gb  = (g * 4 + wave) * 64;
      int p   = gb + lane;
      int row = p >> 3, pos = p & 7;
      int cc  = pos ^ (row & 7);
      gload_lds16(A + (size_t)(tm + row) * K + k0 + cc * 8, (char*)sA + (size_t)gb * 16);
      gload_lds16(W + (size_t)(tn + row) * K + k0 + cc * 8, (char*)sB + (size_t)gb * 16);
    }
    __syncthreads();

#pragma unroll
    for (int t = 0; t < 2; ++t) {
      bf16x8 af[4], bfr[4];
#pragma unroll
      for (int i = 0; i < 4; ++i) {
        int rowa = wm + i * 16 + l16;
        int posa = (t * 4 + quad) ^ (rowa & 7);
        af[i] = *(const bf16x8*)(sA + rowa * GBK + posa * 8);
        int rowb = wn + i * 16 + l16;
        int posb = (t * 4 + quad) ^ (rowb & 7);
        bfr[i] = *(const bf16x8*)(sB + rowb * GBK + posb * 8);
      }
#pragma unroll
      for (int i = 0; i < 4; ++i)
#pragma unroll
        for (int j = 0; j < 4; ++j)
          acc[i][j] = mfma16(af[i], bfr[j], acc[i][j]);
    }
  }

#pragma unroll
  for (int i = 0; i < 4; ++i)
#pragma unroll
    for (int r = 0; r < 4; ++r) {
      int row = tm + wm + i * 16 + quad * 4 + r;
#pragma unroll
      for (int j = 0; j < 4; ++j) {
        int col = tn + wn + j * 16 + l16;
        C[(size_t)row * N + col] = (OT)acc[i][j][r];
      }
    }
}

// ---------------------------------------------------------------------------
// RoPE in-place; Q pre-scaled by 1/sqrt(HD)*log2(e) (exp2-domain softmax).
// ---------------------------------------------------------------------------
__global__ __launch_bounds__(256) void rope_qk(
    bf16* __restrict__ Q, bf16* __restrict__ Kk,
    const float* __restrict__ cosT, const float* __restrict__ sinT)
{
  const float kappa = 0.08838834764831845f * 1.4426950408889634f;
  int t = blockIdx.x * 256 + threadIdx.x;
  int d = t & 63;
  int h = (t >> 6) & (H_ - 1);
  int s = (t >> 10) & (S_ - 1);
  int b = t >> 21;
  size_t base = ((size_t)(b * S_ + s)) * D_ + (size_t)h * HD_;
  float c1 = cosT[s * HD_ + d];
  float s1 = sinT[s * HD_ + d];
  float c2 = cosT[s * HD_ + d + 64];
  float s2 = sinT[s * HD_ + d + 64];
  {
    float x1 = (float)Q[base + d], x2 = (float)Q[base + d + 64];
    Q[base + d]      = (bf16)((x1 * c1 - x2 * s1) * kappa);
    Q[base + d + 64] = (bf16)((x2 * c2 + x1 * s2) * kappa);
  }
  {
    float x1 = (float)Kk[base + d], x2 = (float)Kk[base + d + 64];
    Kk[base + d]      = (bf16)(x1 * c1 - x2 * s1);
    Kk[base + d + 64] = (bf16)(x2 * c2 + x1 * s2);
  }
}

// ---------------------------------------------------------------------------
// V transpose: V[b][s][h*128+d] -> Vt[(b*H+h)*128+d][s]. 64x64 LDS tiles.
// ---------------------------------------------------------------------------
__global__ __launch_bounds__(256) void transpose_v(
    const bf16* __restrict__ V, bf16* __restrict__ Vt)
{
  __shared__ bf16 sT[64 * 72];
  const int tid = threadIdx.x;
  const int si = blockIdx.x;
  const int di = blockIdx.y;
  const int bh = blockIdx.z;
  const int b  = bh >> 4, h = bh & 15;

  const bf16* src = V + (size_t)b * S_ * D_ + (size_t)h * HD_ + di * 64;
  bf16*       dst = Vt + ((size_t)bh * HD_ + di * 64) * S_ + si * 64;

#pragma unroll
  for (int half = 0; half < 2; ++half) {
    int r  = half * 32 + (tid >> 3);
    int c0 = (tid & 7) * 8;
    bf16x8 v = *(const bf16x8*)(src + (size_t)(si * 64 + r) * D_ + c0);
    *(bf16x8*)(sT + r * 72 + c0) = v;
  }
  __syncthreads();
#pragma unroll
  for (int half = 0; half < 2; ++half) {
    int dr = half * 32 + (tid >> 3);
    int c0 = (tid & 7) * 8;
    bf16x8 o;
#pragma unroll
    for (int j = 0; j < 8; ++j) o[j] = sT[(c0 + j) * 72 + dr];
    *(bf16x8*)(dst + (size_t)dr * S_ + c0) = o;
  }
}

// ---------------------------------------------------------------------------
// Flash attention fwd, causal. ABQ=128, ABK=64, 256 threads (4 waves).
// PIPELINED: K double-buffered in LDS; prefetch of tile kt+1 issued right
// after the iter-kt barrier, so the barrier's implicit vmcnt(0) drain waits
// on a load that had a full compute phase in flight (no exposed latency).
// V fragments are read direct-to-register from pre-transposed Vt (L1/L2
// absorb the 4-wave duplication); sVT staging eliminated.
// S^T = K*Q^T (operand swap) keeps softmax in-lane + 2 shuffles.
// sP [128q][72] wave-private A-layout P. One barrier per k-tile.
// ---------------------------------------------------------------------------
#define ABQ 128
#define ABK 64
#define SPS 72

__global__ __launch_bounds__(256, 3) void attn_fwd(
    const bf16* __restrict__ Q, const bf16* __restrict__ K,
    const bf16* __restrict__ Vt, bf16* __restrict__ O)
{
  __shared__ bf16 sK[2][ABK * HD_];  // 2 x 16 KB
  __shared__ bf16 sP[ABQ * SPS];     // 18 KB   (total 50 KB -> 3 blocks/CU)

  const int tid  = threadIdx.x;
  const int wave = tid >> 6, lane = tid & 63;
  const int quad = lane >> 4, l16 = lane & 15;
  const int qb = (int)gridDim.x - 1 - (int)blockIdx.x;   // heavy first
  const int h = blockIdx.y, b = blockIdx.z;

  const bf16* Qh  = Q + (size_t)b * S_ * D_ + (size_t)h * HD_;
  const bf16* Kh  = K + (size_t)b * S_ * D_ + (size_t)h * HD_;
  const bf16* Vth = Vt + ((size_t)(b * H_ + h) * HD_) * S_;
  bf16*       Oh  = O + (size_t)b * S_ * D_ + (size_t)h * HD_;

  const int q0 = qb * ABQ;
  const int wq = wave * 32;
  const int wq_abs = q0 + wq;

  // precomputed staging indices (uniform per thread)
  const int st_row[4] = { (0*256+tid)>>4, (1*256+tid)>>4, (2*256+tid)>>4, (3*256+tid)>>4 };
  const int st_cc[4]  = { (tid&15) ^ (st_row[0]&15), (tid&15) ^ (st_row[1]&15),
                          (tid&15) ^ (st_row[2]&15), (tid&15) ^ (st_row[3]&15) };

  // Q fragments (B operand; layout [n=l16][k=quad*8+j])
  bf16x8 qf[2][4];
#pragma unroll
  for (int i = 0; i < 2; ++i) {
    const bf16* rp = Qh + (size_t)(wq_abs + i * 16 + l16) * D_ + quad * 8;
#pragma unroll
    for (int t = 0; t < 4; ++t) qf[i][t] = *(const bf16x8*)(rp + t * 32);
  }

  f32x4 o_acc[2][8];
#pragma unroll
  for (int i = 0; i < 2; ++i)
#pragma unroll
    for (int j = 0; j < 8; ++j) o_acc[i][j] = (f32x4)0.0f;
  float m_col[2] = {NEG_SENTINEL, NEG_SENTINEL};
  float l_col[2] = {0.0f, 0.0f};

  const int nkt = (q0 + ABQ) / ABK;   // 2*(qb+1)

  // prefetch tile 0 into buf 0
#pragma unroll
  for (int g = 0; g < 4; ++g)
    gload_lds16(Kh + (size_t)st_row[g] * D_ + st_cc[g] * 8,
                (char*)sK[0] + (size_t)(g * 256 + tid) * 16);

  for (int kt = 0; kt < nkt; ++kt) {
    const int kk0 = kt * ABK;
    // implicit vmcnt(0) drain here waits on the PREFETCHED tile (in flight
    // through the previous compute phase); barrier also WAR-frees buf[(kt+1)&1]
    __syncthreads();

    if (kt + 1 < nkt) {
      const int nk0 = kk0 + ABK;
      char* dst = (char*)sK[(kt + 1) & 1];
#pragma unroll
      for (int g = 0; g < 4; ++g)
        gload_lds16(Kh + (size_t)(nk0 + st_row[g]) * D_ + st_cc[g] * 8,
                    dst + (size_t)(g * 256 + tid) * 16);
    }

    const bf16* sKc = sK[kt & 1];

    // waves whose 32 q-rows lie entirely below this key tile skip compute
    if (kk0 <= wq_abs + 31) {
      // S^T = K Q^T : lane holds key=(jt*16+quad*4+r), q-col=l16
      f32x4 st[2][4];
#pragma unroll
      for (int jt = 0; jt < 4; ++jt) {
        bf16x8 kf[4];
#pragma unroll
        for (int t = 0; t < 4; ++t) {
          int pos = (t * 4 + quad) ^ l16;
          kf[t] = *(const bf16x8*)(sKc + (jt * 16 + l16) * HD_ + pos * 8);
        }
#pragma unroll
        for (int i = 0; i < 2; ++i) {
          f32x4 a = (f32x4)0.0f;
#pragma unroll
          for (int t = 0; t < 4; ++t) a = mfma16(kf[t], qf[i][t], a);
          st[i][jt] = a;
        }
      }

      // causal mask only where the tile crosses this wave's diagonal
      if (kk0 + 63 > wq_abs) {
#pragma unroll
        for (int i = 0; i < 2; ++i) {
          int qcol = wq_abs + i * 16 + l16;
#pragma unroll
          for (int jt = 0; jt < 4; ++jt)
#pragma unroll
            for (int r = 0; r < 4; ++r) {
              int key = kk0 + jt * 16 + quad * 4 + r;
              if (key > qcol) st[i][jt][r] = NEG_SENTINEL;
            }
        }
      }

      // online softmax (base-2): in-lane tree + 2 shuffles per reduction
#pragma unroll
      for (int i = 0; i < 2; ++i) {
        float mx = NEG_SENTINEL;
#pragma unroll
        for (int jt = 0; jt < 4; ++jt)
#pragma unroll
          for (int r = 0; r < 4; ++r) mx = fmaxf(mx, st[i][jt][r]);
        mx = fmaxf(mx, __shfl_xor(mx, 16, 64));
        mx = fmaxf(mx, __shfl_xor(mx, 32, 64));
        float m_new = fmaxf(m_col[i], mx);
        float alpha = exp2f(m_col[i] - m_new);
        float ts = 0.0f;
#pragma unroll
        for (int jt = 0; jt < 4; ++jt) {
          bf16x4 pk;
#pragma unroll
          for (int r = 0; r < 4; ++r) {
            float p = exp2f(st[i][jt][r] - m_new);
            ts += p;
            pk[r] = (bf16)p;
          }
          *(bf16x4*)(sP + (wq + i * 16 + l16) * SPS + jt * 16 + quad * 4) = pk;
        }
        ts += __shfl_xor(ts, 16, 64);
        ts += __shfl_xor(ts, 32, 64);
        l_col[i] = l_col[i] * alpha + ts;
        m_col[i] = m_new;
#pragma unroll
        for (int r = 0; r < 4; ++r) {
          float av = __shfl(alpha, quad * 4 + r, 64);
#pragma unroll
          for (int jd = 0; jd < 8; ++jd) o_acc[i][jd][r] *= av;
        }
      }
      // sP rows are wave-private: same-wave LDS RAW needs no barrier.

      // O += P V : P from sP (A-layout), V direct from Vt (B-layout b128s)
#pragma unroll
      for (int ks = 0; ks < 2; ++ks) {
        bf16x8 pf[2], vf[8];
#pragma unroll
        for (int i = 0; i < 2; ++i)
          pf[i] = *(const bf16x8*)(sP + (wq + i * 16 + l16) * SPS + ks * 32 + quad * 8);
#pragma unroll
        for (int jd = 0; jd < 8; ++jd)
          vf[jd] = *(const bf16x8*)(Vth + (size_t)(jd * 16 + l16) * S_ +
                                    kk0 + ks * 32 + quad * 8);
#pragma unroll
        for (int i = 0; i < 2; ++i)
#pragma unroll
          for (int jd = 0; jd < 8; ++jd)
            o_acc[i][jd] = mfma16(pf[i], vf[jd], o_acc[i][jd]);
      }
    }
  }

  // epilogue: fetch denom from q-col lanes, store ctx
#pragma unroll
  for (int i = 0; i < 2; ++i)
#pragma unroll
    for (int r = 0; r < 4; ++r) {
      float lv = __shfl(l_col[i], quad * 4 + r, 64);
      float inv_l = 1.0f / lv;
      int row = wq_abs + i * 16 + quad * 4 + r;
#pragma unroll
      for (int jd = 0; jd < 8; ++jd) {
        int col = jd * 16 + l16;
        Oh[(size_t)row * D_ + col] = (bf16)(o_acc[i][jd][r] * inv_l);
      }
    }
}

// ---------------------------------------------------------------------------
extern "C" void kernel_launch(void* const* d_in, const int* in_sizes, int n_in,
                              void* d_out, int out_size, void* d_ws, size_t ws_size,
                              hipStream_t stream) {
  const float* x    = (const float*)d_in[0];
  const float* Wq   = (const float*)d_in[1];
  const float* Wk   = (const float*)d_in[2];
  const float* Wv   = (const float*)d_in[3];
  const float* Wo   = (const float*)d_in[4];
  const float* cosT = (const float*)d_in[5];
  const float* sinT = (const float*)d_in[6];
  float* out = (float*)d_out;

  const size_t NE = (size_t)B_ * S_ * D_;   // 8,388,608
  const size_t WE = (size_t)D_ * D_;        // 4,194,304
  bf16* Qb    = (bf16*)d_ws;                // ws: Q|K|V|C|Wslot = 72 MB
  bf16* Kb    = Qb + NE;
  bf16* Vb    = Kb + NE;
  bf16* Cb    = Vb + NE;                    // bf16(x) -> later Vt
  bf16* Wslot = Cb + NE;

  const int M = B_ * S_;
  dim3 gg(D_ / GTN, M / GTM);               // (16, 32)
  const int cvtX = (int)(NE / 1024);
  const int cvtW = (int)(WE / 1024);

  cvt_f32_bf16<<<cvtX, 256, 0, stream>>>(x, Cb);
  cvt_f32_bf16<<<cvtW, 256, 0, stream>>>(Wq, Wslot);
  gemm_xwt<bf16><<<gg, 256, 0, stream>>>(Cb, Wslot, Qb, M, D_, D_);
  cvt_f32_bf16<<<cvtW, 256, 0, stream>>>(Wk, Wslot);
  gemm_xwt<bf16><<<gg, 256, 0, stream>>>(Cb, Wslot, Kb, M, D_, D_);
  cvt_f32_bf16<<<cvtW, 256, 0, stream>>>(Wv, Wslot);
  gemm_xwt<bf16><<<gg, 256, 0, stream>>>(Cb, Wslot, Vb, M, D_, D_);
  rope_qk<<<(B_ * S_ * H_ * 64) / 256, 256, 0, stream>>>(Qb, Kb, cosT, sinT);
  // x (Cb) dead: transpose V into Cb, ctx goes into Vb.
  transpose_v<<<dim3(32, 2, 32), 256, 0, stream>>>(Vb, Cb);
  attn_fwd<<<dim3(S_ / ABQ, H_, B_), 256, 0, stream>>>(Qb, Kb, Cb, Vb);
  cvt_f32_bf16<<<cvtW, 256, 0, stream>>>(Wo, Wslot);
  gemm_xwt<float><<<gg, 256, 0, stream>>>(Vb, Wslot, out, M, D_, D_);
}

// Round 7
// 535.154 us; speedup vs baseline: 1.2044x; 1.2044x over previous
//
#include <hip/hip_runtime.h>
#include <cstdint>
#include <cmath>

#define B_ 2
#define S_ 2048
#define D_ 2048
#define H_ 16
#define HD_ 128

#define NEG_SENTINEL -1.0e30f

typedef __bf16 bf16;
typedef __attribute__((ext_vector_type(4))) __bf16 bf16x4;
typedef __attribute__((ext_vector_type(8))) __bf16 bf16x8;
typedef __attribute__((ext_vector_type(4))) float f32x4;

__device__ __forceinline__ void gload_lds16(const void* g, void* l) {
  __builtin_amdgcn_global_load_lds(
      (const __attribute__((address_space(1))) unsigned int*)g,
      (__attribute__((address_space(3))) unsigned int*)l, 16, 0, 0);
}

__device__ __forceinline__ f32x4 mfma16(bf16x8 a, bf16x8 b, f32x4 c) {
  return __builtin_amdgcn_mfma_f32_16x16x32_bf16(a, b, c, 0, 0, 0);
}

// ---------------------------------------------------------------------------
// fp32 -> bf16 convert. One thread = 4 elements.
// ---------------------------------------------------------------------------
__global__ __launch_bounds__(256) void cvt_f32_bf16(
    const float* __restrict__ in, bf16* __restrict__ out)
{
  int i = blockIdx.x * 256 + threadIdx.x;
  f32x4 v = ((const f32x4*)in)[i];
  bf16x4 o;
#pragma unroll
  for (int j = 0; j < 4; ++j) o[j] = (bf16)v[j];
  ((bf16x4*)out)[i] = o;
}

// ---------------------------------------------------------------------------
// GEMM: C[m][n] = sum_k A[m][k] * W[n][k], bf16 in, fp32 acc, OT out.
// 128x128 tile, BK=64, XOR chunk swizzle. (verified round 3)
// ---------------------------------------------------------------------------
#define GTM 128
#define GTN 128
#define GBK 64

template <typename OT>
__global__ __launch_bounds__(256) void gemm_xwt(
    const bf16* __restrict__ A, const bf16* __restrict__ W, OT* __restrict__ C,
    int M, int N, int K)
{
  __shared__ bf16 sA[GTM * GBK];
  __shared__ bf16 sB[GTN * GBK];
  const int tid  = threadIdx.x;
  const int wave = tid >> 6, lane = tid & 63;
  const int quad = lane >> 4, l16 = lane & 15;
  const int tm = blockIdx.y * GTM;
  const int tn = blockIdx.x * GTN;
  const int wm = (wave >> 1) * 64, wn = (wave & 1) * 64;

  f32x4 acc[4][4];
#pragma unroll
  for (int i = 0; i < 4; ++i)
#pragma unroll
    for (int j = 0; j < 4; ++j) acc[i][j] = (f32x4)0.0f;

  for (int k0 = 0; k0 < K; k0 += GBK) {
    __syncthreads();
#pragma unroll
    for (int g = 0; g < 4; ++g) {
      int gb  = (g * 4 + wave) * 64;
      int p   = gb + lane;
      int row = p >> 3, pos = p & 7;
      int cc  = pos ^ (row & 7);
      gload_lds16(A + (size_t)(tm + row) * K + k0 + cc * 8, (char*)sA + (size_t)gb * 16);
      gload_lds16(W + (size_t)(tn + row) * K + k0 + cc * 8, (char*)sB + (size_t)gb * 16);
    }
    __syncthreads();

#pragma unroll
    for (int t = 0; t < 2; ++t) {
      bf16x8 af[4], bfr[4];
#pragma unroll
      for (int i = 0; i < 4; ++i) {
        int rowa = wm + i * 16 + l16;
        int posa = (t * 4 + quad) ^ (rowa & 7);
        af[i] = *(const bf16x8*)(sA + rowa * GBK + posa * 8);
        int rowb = wn + i * 16 + l16;
        int posb = (t * 4 + quad) ^ (rowb & 7);
        bfr[i] = *(const bf16x8*)(sB + rowb * GBK + posb * 8);
      }
#pragma unroll
      for (int i = 0; i < 4; ++i)
#pragma unroll
        for (int j = 0; j < 4; ++j)
          acc[i][j] = mfma16(af[i], bfr[j], acc[i][j]);
    }
  }

#pragma unroll
  for (int i = 0; i < 4; ++i)
#pragma unroll
    for (int r = 0; r < 4; ++r) {
      int row = tm + wm + i * 16 + quad * 4 + r;
#pragma unroll
      for (int j = 0; j < 4; ++j) {
        int col = tn + wn + j * 16 + l16;
        C[(size_t)row * N + col] = (OT)acc[i][j][r];
      }
    }
}

// ---------------------------------------------------------------------------
// RoPE in-place; Q pre-scaled by 1/sqrt(HD)*log2(e) (exp2-domain softmax).
// ---------------------------------------------------------------------------
__global__ __launch_bounds__(256) void rope_qk(
    bf16* __restrict__ Q, bf16* __restrict__ Kk,
    const float* __restrict__ cosT, const float* __restrict__ sinT)
{
  const float kappa = 0.08838834764831845f * 1.4426950408889634f;
  int t = blockIdx.x * 256 + threadIdx.x;
  int d = t & 63;
  int h = (t >> 6) & (H_ - 1);
  int s = (t >> 10) & (S_ - 1);
  int b = t >> 21;
  size_t base = ((size_t)(b * S_ + s)) * D_ + (size_t)h * HD_;
  float c1 = cosT[s * HD_ + d];
  float s1 = sinT[s * HD_ + d];
  float c2 = cosT[s * HD_ + d + 64];
  float s2 = sinT[s * HD_ + d + 64];
  {
    float x1 = (float)Q[base + d], x2 = (float)Q[base + d + 64];
    Q[base + d]      = (bf16)((x1 * c1 - x2 * s1) * kappa);
    Q[base + d + 64] = (bf16)((x2 * c2 + x1 * s2) * kappa);
  }
  {
    float x1 = (float)Kk[base + d], x2 = (float)Kk[base + d + 64];
    Kk[base + d]      = (bf16)(x1 * c1 - x2 * s1);
    Kk[base + d + 64] = (bf16)(x2 * c2 + x1 * s2);
  }
}

// ---------------------------------------------------------------------------
// V transpose: V[b][s][h*128+d] -> Vt[(b*H+h)*128+d][s]. 64x64 LDS tiles.
// ---------------------------------------------------------------------------
__global__ __launch_bounds__(256) void transpose_v(
    const bf16* __restrict__ V, bf16* __restrict__ Vt)
{
  __shared__ bf16 sT[64 * 72];
  const int tid = threadIdx.x;
  const int si = blockIdx.x;
  const int di = blockIdx.y;
  const int bh = blockIdx.z;
  const int b  = bh >> 4, h = bh & 15;

  const bf16* src = V + (size_t)b * S_ * D_ + (size_t)h * HD_ + di * 64;
  bf16*       dst = Vt + ((size_t)bh * HD_ + di * 64) * S_ + si * 64;

#pragma unroll
  for (int half = 0; half < 2; ++half) {
    int r  = half * 32 + (tid >> 3);
    int c0 = (tid & 7) * 8;
    bf16x8 v = *(const bf16x8*)(src + (size_t)(si * 64 + r) * D_ + c0);
    *(bf16x8*)(sT + r * 72 + c0) = v;
  }
  __syncthreads();
#pragma unroll
  for (int half = 0; half < 2; ++half) {
    int dr = half * 32 + (tid >> 3);
    int c0 = (tid & 7) * 8;
    bf16x8 o;
#pragma unroll
    for (int j = 0; j < 8; ++j) o[j] = sT[(c0 + j) * 72 + dr];
    *(bf16x8*)(dst + (size_t)dr * S_ + c0) = o;
  }
}

// ---------------------------------------------------------------------------
// Flash attention fwd, causal. ABQ=128, ABK=64, 256 threads (4 waves).
// PIPELINED with correct in-order-vmcnt issue discipline:
//   barrier -> issue V direct loads (this tile) -> issue K prefetch (next
//   tile, global_load_lds into the other LDS buffer) -> QK from LDS
//   (lgkm-only waits) -> softmax -> PV consumes V regs at vmcnt(4), leaving
//   the 4 prefetch ops in flight across the next barrier.
// No min-waves bound (round 6's cap at 84 VGPR caused scratch spills).
// S^T = K*Q^T (operand swap) keeps softmax in-lane + 2 shuffles.
// sP [128q][72] wave-private A-layout P. One barrier per k-tile.
// ---------------------------------------------------------------------------
#define ABQ 128
#define ABK 64
#define SPS 72

__global__ __launch_bounds__(256) void attn_fwd(
    const bf16* __restrict__ Q, const bf16* __restrict__ K,
    const bf16* __restrict__ Vt, bf16* __restrict__ O)
{
  __shared__ bf16 sK[2][ABK * HD_];  // 2 x 16 KB
  __shared__ bf16 sP[ABQ * SPS];     // 18 KB   (total 50 KB)

  const int tid  = threadIdx.x;
  const int wave = tid >> 6, lane = tid & 63;
  const int quad = lane >> 4, l16 = lane & 15;
  const int qb = (int)gridDim.x - 1 - (int)blockIdx.x;   // heavy first
  const int h = blockIdx.y, b = blockIdx.z;

  const bf16* Qh  = Q + (size_t)b * S_ * D_ + (size_t)h * HD_;
  const bf16* Kh  = K + (size_t)b * S_ * D_ + (size_t)h * HD_;
  const bf16* Vth = Vt + ((size_t)(b * H_ + h) * HD_) * S_;
  bf16*       Oh  = O + (size_t)b * S_ * D_ + (size_t)h * HD_;

  const int q0 = qb * ABQ;
  const int wq = wave * 32;
  const int wq_abs = q0 + wq;

  const int st_row[4] = { (0*256+tid)>>4, (1*256+tid)>>4, (2*256+tid)>>4, (3*256+tid)>>4 };
  const int st_cc[4]  = { (tid&15) ^ (st_row[0]&15), (tid&15) ^ (st_row[1]&15),
                          (tid&15) ^ (st_row[2]&15), (tid&15) ^ (st_row[3]&15) };

  // Q fragments (B operand; layout [n=l16][k=quad*8+j])
  bf16x8 qf[2][4];
#pragma unroll
  for (int i = 0; i < 2; ++i) {
    const bf16* rp = Qh + (size_t)(wq_abs + i * 16 + l16) * D_ + quad * 8;
#pragma unroll
    for (int t = 0; t < 4; ++t) qf[i][t] = *(const bf16x8*)(rp + t * 32);
  }

  f32x4 o_acc[2][8];
#pragma unroll
  for (int i = 0; i < 2; ++i)
#pragma unroll
    for (int j = 0; j < 8; ++j) o_acc[i][j] = (f32x4)0.0f;
  float m_col[2] = {NEG_SENTINEL, NEG_SENTINEL};
  float l_col[2] = {0.0f, 0.0f};

  const int nkt = (q0 + ABQ) / ABK;   // 2*(qb+1)

  // prefetch tile 0 into buf 0
#pragma unroll
  for (int g = 0; g < 4; ++g)
    gload_lds16(Kh + (size_t)st_row[g] * D_ + st_cc[g] * 8,
                (char*)sK[0] + (size_t)(g * 256 + tid) * 16);

  for (int kt = 0; kt < nkt; ++kt) {
    const int kk0 = kt * ABK;
    __syncthreads();   // waits on prefetched K (had full compute phase in flight)

    const bool active = (kk0 <= wq_abs + 31);

    // 1) V direct loads FIRST (in-order vmcnt: their use won't drain prefetch)
    bf16x8 vf[2][8];
    if (active) {
#pragma unroll
      for (int ks = 0; ks < 2; ++ks)
#pragma unroll
        for (int jd = 0; jd < 8; ++jd)
          vf[ks][jd] = *(const bf16x8*)(Vth + (size_t)(jd * 16 + l16) * S_ +
                                        kk0 + ks * 32 + quad * 8);
    }

    // 2) K prefetch for next tile (issued last -> stays in flight)
    if (kt + 1 < nkt) {
      const int nk0 = kk0 + ABK;
      char* dst = (char*)sK[(kt + 1) & 1];
#pragma unroll
      for (int g = 0; g < 4; ++g)
        gload_lds16(Kh + (size_t)(nk0 + st_row[g]) * D_ + st_cc[g] * 8,
                    dst + (size_t)(g * 256 + tid) * 16);
    }

    const bf16* sKc = sK[kt & 1];

    if (active) {
      // S^T = K Q^T : lane holds key=(jt*16+quad*4+r), q-col=l16
      f32x4 st[2][4];
#pragma unroll
      for (int jt = 0; jt < 4; ++jt) {
        bf16x8 kf[4];
#pragma unroll
        for (int t = 0; t < 4; ++t) {
          int pos = (t * 4 + quad) ^ l16;
          kf[t] = *(const bf16x8*)(sKc + (jt * 16 + l16) * HD_ + pos * 8);
        }
#pragma unroll
        for (int i = 0; i < 2; ++i) {
          f32x4 a = (f32x4)0.0f;
#pragma unroll
          for (int t = 0; t < 4; ++t) a = mfma16(kf[t], qf[i][t], a);
          st[i][jt] = a;
        }
      }

      // causal mask only where the tile crosses this wave's diagonal
      if (kk0 + 63 > wq_abs) {
#pragma unroll
        for (int i = 0; i < 2; ++i) {
          int qcol = wq_abs + i * 16 + l16;
#pragma unroll
          for (int jt = 0; jt < 4; ++jt)
#pragma unroll
            for (int r = 0; r < 4; ++r) {
              int key = kk0 + jt * 16 + quad * 4 + r;
              if (key > qcol) st[i][jt][r] = NEG_SENTINEL;
            }
        }
      }

      // online softmax (base-2): in-lane tree + 2 shuffles per reduction
#pragma unroll
      for (int i = 0; i < 2; ++i) {
        float mx = NEG_SENTINEL;
#pragma unroll
        for (int jt = 0; jt < 4; ++jt)
#pragma unroll
          for (int r = 0; r < 4; ++r) mx = fmaxf(mx, st[i][jt][r]);
        mx = fmaxf(mx, __shfl_xor(mx, 16, 64));
        mx = fmaxf(mx, __shfl_xor(mx, 32, 64));
        float m_new = fmaxf(m_col[i], mx);
        float alpha = exp2f(m_col[i] - m_new);
        float ts = 0.0f;
#pragma unroll
        for (int jt = 0; jt < 4; ++jt) {
          bf16x4 pk;
#pragma unroll
          for (int r = 0; r < 4; ++r) {
            float p = exp2f(st[i][jt][r] - m_new);
            ts += p;
            pk[r] = (bf16)p;
          }
          *(bf16x4*)(sP + (wq + i * 16 + l16) * SPS + jt * 16 + quad * 4) = pk;
        }
        ts += __shfl_xor(ts, 16, 64);
        ts += __shfl_xor(ts, 32, 64);
        l_col[i] = l_col[i] * alpha + ts;
        m_col[i] = m_new;
#pragma unroll
        for (int r = 0; r < 4; ++r) {
          float av = __shfl(alpha, quad * 4 + r, 64);
#pragma unroll
          for (int jd = 0; jd < 8; ++jd) o_acc[i][jd][r] *= av;
        }
      }
      // sP rows are wave-private: same-wave LDS RAW needs no barrier.

      // O += P V : P from sP (A-layout), V from registers (vmcnt(4) waits)
#pragma unroll
      for (int ks = 0; ks < 2; ++ks) {
        bf16x8 pf[2];
#pragma unroll
        for (int i = 0; i < 2; ++i)
          pf[i] = *(const bf16x8*)(sP + (wq + i * 16 + l16) * SPS + ks * 32 + quad * 8);
#pragma unroll
        for (int i = 0; i < 2; ++i)
#pragma unroll
          for (int jd = 0; jd < 8; ++jd)
            o_acc[i][jd] = mfma16(pf[i], vf[ks][jd], o_acc[i][jd]);
      }
    }
  }

  // epilogue: fetch denom from q-col lanes, store ctx
#pragma unroll
  for (int i = 0; i < 2; ++i)
#pragma unroll
    for (int r = 0; r < 4; ++r) {
      float lv = __shfl(l_col[i], quad * 4 + r, 64);
      float inv_l = 1.0f / lv;
      int row = wq_abs + i * 16 + quad * 4 + r;
#pragma unroll
      for (int jd = 0; jd < 8; ++jd) {
        int col = jd * 16 + l16;
        Oh[(size_t)row * D_ + col] = (bf16)(o_acc[i][jd][r] * inv_l);
      }
    }
}

// ---------------------------------------------------------------------------
extern "C" void kernel_launch(void* const* d_in, const int* in_sizes, int n_in,
                              void* d_out, int out_size, void* d_ws, size_t ws_size,
                              hipStream_t stream) {
  const float* x    = (const float*)d_in[0];
  const float* Wq   = (const float*)d_in[1];
  const float* Wk   = (const float*)d_in[2];
  const float* Wv   = (const float*)d_in[3];
  const float* Wo   = (const float*)d_in[4];
  const float* cosT = (const float*)d_in[5];
  const float* sinT = (const float*)d_in[6];
  float* out = (float*)d_out;

  const size_t NE = (size_t)B_ * S_ * D_;   // 8,388,608
  const size_t WE = (size_t)D_ * D_;        // 4,194,304
  bf16* Qb    = (bf16*)d_ws;                // ws: Q|K|V|C|Wslot = 72 MB
  bf16* Kb    = Qb + NE;
  bf16* Vb    = Kb + NE;
  bf16* Cb    = Vb + NE;                    // bf16(x) -> later Vt
  bf16* Wslot = Cb + NE;

  const int M = B_ * S_;
  dim3 gg(D_ / GTN, M / GTM);               // (16, 32)
  const int cvtX = (int)(NE / 1024);
  const int cvtW = (int)(WE / 1024);

  cvt_f32_bf16<<<cvtX, 256, 0, stream>>>(x, Cb);
  cvt_f32_bf16<<<cvtW, 256, 0, stream>>>(Wq, Wslot);
  gemm_xwt<bf16><<<gg, 256, 0, stream>>>(Cb, Wslot, Qb, M, D_, D_);
  cvt_f32_bf16<<<cvtW, 256, 0, stream>>>(Wk, Wslot);
  gemm_xwt<bf16><<<gg, 256, 0, stream>>>(Cb, Wslot, Kb, M, D_, D_);
  cvt_f32_bf16<<<cvtW, 256, 0, stream>>>(Wv, Wslot);
  gemm_xwt<bf16><<<gg, 256, 0, stream>>>(Cb, Wslot, Vb, M, D_, D_);
  rope_qk<<<(B_ * S_ * H_ * 64) / 256, 256, 0, stream>>>(Qb, Kb, cosT, sinT);
  // x (Cb) dead: transpose V into Cb, ctx goes into Vb.
  transpose_v<<<dim3(32, 2, 32), 256, 0, stream>>>(Vb, Cb);
  attn_fwd<<<dim3(S_ / ABQ, H_, B_), 256, 0, stream>>>(Qb, Kb, Cb, Vb);
  cvt_f32_bf16<<<cvtW, 256, 0, stream>>>(Wo, Wslot);
  gemm_xwt<float><<<gg, 256, 0, stream>>>(Vb, Wslot, out, M, D_, D_);
}

// Round 8
// 480.170 us; speedup vs baseline: 1.3424x; 1.1145x over previous
//
#include <hip/hip_runtime.h>
#include <cstdint>
#include <cmath>

#define B_ 2
#define S_ 2048
#define D_ 2048
#define H_ 16
#define HD_ 128

#define NEG_SENTINEL -1.0e30f

typedef __bf16 bf16;
typedef __attribute__((ext_vector_type(4))) __bf16 bf16x4;
typedef __attribute__((ext_vector_type(8))) __bf16 bf16x8;
typedef __attribute__((ext_vector_type(4))) float f32x4;

__device__ __forceinline__ void gload_lds16(const void* g, void* l) {
  __builtin_amdgcn_global_load_lds(
      (const __attribute__((address_space(1))) unsigned int*)g,
      (__attribute__((address_space(3))) unsigned int*)l, 16, 0, 0);
}

__device__ __forceinline__ f32x4 mfma16(bf16x8 a, bf16x8 b, f32x4 c) {
  return __builtin_amdgcn_mfma_f32_16x16x32_bf16(a, b, c, 0, 0, 0);
}

// ---------------------------------------------------------------------------
// fp32 -> bf16 convert. One thread = 4 elements.
// ---------------------------------------------------------------------------
__global__ __launch_bounds__(256) void cvt_f32_bf16(
    const float* __restrict__ in, bf16* __restrict__ out)
{
  int i = blockIdx.x * 256 + threadIdx.x;
  f32x4 v = ((const f32x4*)in)[i];
  bf16x4 o;
#pragma unroll
  for (int j = 0; j < 4; ++j) o[j] = (bf16)v[j];
  ((bf16x4*)out)[i] = o;
}

// ---------------------------------------------------------------------------
// GEMM: C[m][n] = sum_k A[m][k] * W[n][k], bf16 in, fp32 acc, OT out.
// 128x128 tile, BK=64, XOR chunk swizzle. (verified round 3)
// ---------------------------------------------------------------------------
#define GTM 128
#define GTN 128
#define GBK 64

template <typename OT>
__global__ __launch_bounds__(256) void gemm_xwt(
    const bf16* __restrict__ A, const bf16* __restrict__ W, OT* __restrict__ C,
    int M, int N, int K)
{
  __shared__ bf16 sA[GTM * GBK];
  __shared__ bf16 sB[GTN * GBK];
  const int tid  = threadIdx.x;
  const int wave = tid >> 6, lane = tid & 63;
  const int quad = lane >> 4, l16 = lane & 15;
  const int tm = blockIdx.y * GTM;
  const int tn = blockIdx.x * GTN;
  const int wm = (wave >> 1) * 64, wn = (wave & 1) * 64;

  f32x4 acc[4][4];
#pragma unroll
  for (int i = 0; i < 4; ++i)
#pragma unroll
    for (int j = 0; j < 4; ++j) acc[i][j] = (f32x4)0.0f;

  for (int k0 = 0; k0 < K; k0 += GBK) {
    __syncthreads();
#pragma unroll
    for (int g = 0; g < 4; ++g) {
      int gb  = (g * 4 + wave) * 64;
      int p   = gb + lane;
      int row = p >> 3, pos = p & 7;
      int cc  = pos ^ (row & 7);
      gload_lds16(A + (size_t)(tm + row) * K + k0 + cc * 8, (char*)sA + (size_t)gb * 16);
      gload_lds16(W + (size_t)(tn + row) * K + k0 + cc * 8, (char*)sB + (size_t)gb * 16);
    }
    __syncthreads();

#pragma unroll
    for (int t = 0; t < 2; ++t) {
      bf16x8 af[4], bfr[4];
#pragma unroll
      for (int i = 0; i < 4; ++i) {
        int rowa = wm + i * 16 + l16;
        int posa = (t * 4 + quad) ^ (rowa & 7);
        af[i] = *(const bf16x8*)(sA + rowa * GBK + posa * 8);
        int rowb = wn + i * 16 + l16;
        int posb = (t * 4 + quad) ^ (rowb & 7);
        bfr[i] = *(const bf16x8*)(sB + rowb * GBK + posb * 8);
      }
#pragma unroll
      for (int i = 0; i < 4; ++i)
#pragma unroll
        for (int j = 0; j < 4; ++j)
          acc[i][j] = mfma16(af[i], bfr[j], acc[i][j]);
    }
  }

#pragma unroll
  for (int i = 0; i < 4; ++i)
#pragma unroll
    for (int r = 0; r < 4; ++r) {
      int row = tm + wm + i * 16 + quad * 4 + r;
#pragma unroll
      for (int j = 0; j < 4; ++j) {
        int col = tn + wn + j * 16 + l16;
        C[(size_t)row * N + col] = (OT)acc[i][j][r];
      }
    }
}

// ---------------------------------------------------------------------------
// RoPE in-place; Q pre-scaled by 1/sqrt(HD)*log2(e) (exp2-domain softmax).
// ---------------------------------------------------------------------------
__global__ __launch_bounds__(256) void rope_qk(
    bf16* __restrict__ Q, bf16* __restrict__ Kk,
    const float* __restrict__ cosT, const float* __restrict__ sinT)
{
  const float kappa = 0.08838834764831845f * 1.4426950408889634f;
  int t = blockIdx.x * 256 + threadIdx.x;
  int d = t & 63;
  int h = (t >> 6) & (H_ - 1);
  int s = (t >> 10) & (S_ - 1);
  int b = t >> 21;
  size_t base = ((size_t)(b * S_ + s)) * D_ + (size_t)h * HD_;
  float c1 = cosT[s * HD_ + d];
  float s1 = sinT[s * HD_ + d];
  float c2 = cosT[s * HD_ + d + 64];
  float s2 = sinT[s * HD_ + d + 64];
  {
    float x1 = (float)Q[base + d], x2 = (float)Q[base + d + 64];
    Q[base + d]      = (bf16)((x1 * c1 - x2 * s1) * kappa);
    Q[base + d + 64] = (bf16)((x2 * c2 + x1 * s2) * kappa);
  }
  {
    float x1 = (float)Kk[base + d], x2 = (float)Kk[base + d + 64];
    Kk[base + d]      = (bf16)(x1 * c1 - x2 * s1);
    Kk[base + d + 64] = (bf16)(x2 * c2 + x1 * s2);
  }
}

// ---------------------------------------------------------------------------
// V transpose: V[b][s][h*128+d] -> Vt[(b*H+h)*128+d][s]. 64x64 LDS tiles.
// ---------------------------------------------------------------------------
__global__ __launch_bounds__(256) void transpose_v(
    const bf16* __restrict__ V, bf16* __restrict__ Vt)
{
  __shared__ bf16 sT[64 * 72];
  const int tid = threadIdx.x;
  const int si = blockIdx.x;
  const int di = blockIdx.y;
  const int bh = blockIdx.z;
  const int b  = bh >> 4, h = bh & 15;

  const bf16* src = V + (size_t)b * S_ * D_ + (size_t)h * HD_ + di * 64;
  bf16*       dst = Vt + ((size_t)bh * HD_ + di * 64) * S_ + si * 64;

#pragma unroll
  for (int half = 0; half < 2; ++half) {
    int r  = half * 32 + (tid >> 3);
    int c0 = (tid & 7) * 8;
    bf16x8 v = *(const bf16x8*)(src + (size_t)(si * 64 + r) * D_ + c0);
    *(bf16x8*)(sT + r * 72 + c0) = v;
  }
  __syncthreads();
#pragma unroll
  for (int half = 0; half < 2; ++half) {
    int dr = half * 32 + (tid >> 3);
    int c0 = (tid & 7) * 8;
    bf16x8 o;
#pragma unroll
    for (int j = 0; j < 8; ++j) o[j] = sT[(c0 + j) * 72 + dr];
    *(bf16x8*)(dst + (size_t)dr * S_ + c0) = o;
  }
}

// ---------------------------------------------------------------------------
// Flash attention fwd, causal. ABQ=128, ABK=64, 256 threads (4 waves).
// Round-5 structure (best measured: staged sK+sVT via global_load_lds,
// 2 barriers/iter, S^T=K*Q^T softmax, wave-private sP) + XCD-AWARE SWIZZLE:
// flat 512-block grid, lin = (col%8) + 8*(qx + 16*(col>>3)) so all 16
// q-blocks of one (b,h) column land on ONE XCD (assuming XCD = lin%8
// dispatch). Each XCD then holds 4 columns = 4MB K+V = its entire L2,
// turning per-iter staging drains from HBM (~900cyc) into L2 hits.
// ---------------------------------------------------------------------------
#define ABQ 128
#define ABK 64
#define SPS 72

__global__ __launch_bounds__(256) void attn_fwd(
    const bf16* __restrict__ Q, const bf16* __restrict__ K,
    const bf16* __restrict__ Vt, bf16* __restrict__ O)
{
  __shared__ bf16 sK[ABK * HD_];     // 16 KB
  __shared__ bf16 sVT[HD_ * ABK];    // 16 KB
  __shared__ bf16 sP[ABQ * SPS];     // 18 KB  (total 50 KB -> 3 blocks/CU)

  const int tid  = threadIdx.x;
  const int wave = tid >> 6, lane = tid & 63;
  const int quad = lane >> 4, l16 = lane & 15;

  // XCD-locality decode: col = b*H+h owns XCD col%8; qx heavy-first.
  const int lin   = (int)blockIdx.x;
  const int low3  = lin & 7;
  const int rest  = lin >> 3;
  const int qx    = rest & 15;
  const int colhi = rest >> 4;            // 0..3
  const int col   = low3 + (colhi << 3);  // 0..31
  const int b = col >> 4, h = col & 15;
  const int qb = 15 - qx;                 // heavy blocks dispatched first

  const bf16* Qh  = Q + (size_t)b * S_ * D_ + (size_t)h * HD_;
  const bf16* Kh  = K + (size_t)b * S_ * D_ + (size_t)h * HD_;
  const bf16* Vth = Vt + ((size_t)(b * H_ + h) * HD_) * S_;
  bf16*       Oh  = O + (size_t)b * S_ * D_ + (size_t)h * HD_;

  const int q0 = qb * ABQ;
  const int wq = wave * 32;
  const int wq_abs = q0 + wq;

  // Q fragments (B operand; layout [n=l16][k=quad*8+j])
  bf16x8 qf[2][4];
#pragma unroll
  for (int i = 0; i < 2; ++i) {
    const bf16* rp = Qh + (size_t)(wq_abs + i * 16 + l16) * D_ + quad * 8;
#pragma unroll
    for (int t = 0; t < 4; ++t) qf[i][t] = *(const bf16x8*)(rp + t * 32);
  }

  f32x4 o_acc[2][8];
#pragma unroll
  for (int i = 0; i < 2; ++i)
#pragma unroll
    for (int j = 0; j < 8; ++j) o_acc[i][j] = (f32x4)0.0f;
  float m_col[2] = {NEG_SENTINEL, NEG_SENTINEL};
  float l_col[2] = {0.0f, 0.0f};

  const int nkt = (q0 + ABQ) / ABK;   // 2*(qb+1)
  for (int kt = 0; kt < nkt; ++kt) {
    const int kk0 = kt * ABK;
    __syncthreads();   // all waves done with sK/sVT before restage

    // stage K: 1024 chunks over 256 threads, pos = cc ^ (row&15)
#pragma unroll
    for (int g = 0; g < 4; ++g) {
      int p   = g * 256 + tid;
      int row = p >> 4, pos = p & 15;
      int cc  = pos ^ (row & 15);
      gload_lds16(Kh + (size_t)(kk0 + row) * D_ + cc * 8, (char*)sK + (size_t)p * 16);
    }
    // stage V^T from Vt: 1024 chunks, pos = cc ^ (d&7)
#pragma unroll
    for (int g = 0; g < 4; ++g) {
      int p  = g * 256 + tid;
      int d  = p >> 3, pos = p & 7;
      int cc = pos ^ (d & 7);
      gload_lds16(Vth + (size_t)d * S_ + kk0 + cc * 8, (char*)sVT + (size_t)p * 16);
    }
    __syncthreads();   // drain global_load_lds

    // waves whose 32 q-rows are entirely below this key tile skip compute
    if (kk0 <= wq_abs + 31) {
      // S^T = K Q^T : lane holds key=(jt*16+quad*4+r), q-col=l16
      f32x4 st[2][4];
#pragma unroll
      for (int jt = 0; jt < 4; ++jt) {
        bf16x8 kf[4];
#pragma unroll
        for (int t = 0; t < 4; ++t) {
          int pos = (t * 4 + quad) ^ l16;
          kf[t] = *(const bf16x8*)(sK + (jt * 16 + l16) * HD_ + pos * 8);
        }
#pragma unroll
        for (int i = 0; i < 2; ++i) {
          f32x4 a = (f32x4)0.0f;
#pragma unroll
          for (int t = 0; t < 4; ++t) a = mfma16(kf[t], qf[i][t], a);
          st[i][jt] = a;
        }
      }

      // causal mask only where the tile crosses this wave's diagonal
      if (kk0 + 63 > wq_abs) {
#pragma unroll
        for (int i = 0; i < 2; ++i) {
          int qcol = wq_abs + i * 16 + l16;
#pragma unroll
          for (int jt = 0; jt < 4; ++jt)
#pragma unroll
            for (int r = 0; r < 4; ++r) {
              int key = kk0 + jt * 16 + quad * 4 + r;
              if (key > qcol) st[i][jt][r] = NEG_SENTINEL;
            }
        }
      }

      // online softmax (base-2), in-lane tree + 2 shuffles per reduction
#pragma unroll
      for (int i = 0; i < 2; ++i) {
        float mx = NEG_SENTINEL;
#pragma unroll
        for (int jt = 0; jt < 4; ++jt)
#pragma unroll
          for (int r = 0; r < 4; ++r) mx = fmaxf(mx, st[i][jt][r]);
        mx = fmaxf(mx, __shfl_xor(mx, 16, 64));
        mx = fmaxf(mx, __shfl_xor(mx, 32, 64));
        float m_new = fmaxf(m_col[i], mx);
        float alpha = exp2f(m_col[i] - m_new);
        float ts = 0.0f;
#pragma unroll
        for (int jt = 0; jt < 4; ++jt) {
          bf16x4 pk;
#pragma unroll
          for (int r = 0; r < 4; ++r) {
            float p = exp2f(st[i][jt][r] - m_new);
            ts += p;
            pk[r] = (bf16)p;
          }
          *(bf16x4*)(sP + (wq + i * 16 + l16) * SPS + jt * 16 + quad * 4) = pk;
        }
        ts += __shfl_xor(ts, 16, 64);
        ts += __shfl_xor(ts, 32, 64);
        l_col[i] = l_col[i] * alpha + ts;
        m_col[i] = m_new;
#pragma unroll
        for (int r = 0; r < 4; ++r) {
          float av = __shfl(alpha, quad * 4 + r, 64);
#pragma unroll
          for (int jd = 0; jd < 8; ++jd) o_acc[i][jd][r] *= av;
        }
      }
      // sP rows are wave-private: same-wave LDS RAW needs no barrier.

      // O += P V  (two 32-key steps)
#pragma unroll
      for (int ks = 0; ks < 2; ++ks) {
        bf16x8 pf[2], vf[8];
#pragma unroll
        for (int i = 0; i < 2; ++i)
          pf[i] = *(const bf16x8*)(sP + (wq + i * 16 + l16) * SPS + ks * 32 + quad * 8);
#pragma unroll
        for (int jd = 0; jd < 8; ++jd) {
          int pos = (ks * 4 + quad) ^ (l16 & 7);
          vf[jd] = *(const bf16x8*)(sVT + (jd * 16 + l16) * ABK + pos * 8);
        }
#pragma unroll
        for (int i = 0; i < 2; ++i)
#pragma unroll
          for (int jd = 0; jd < 8; ++jd)
            o_acc[i][jd] = mfma16(pf[i], vf[jd], o_acc[i][jd]);
      }
    }
  }

  // epilogue: fetch denom from q-col lanes, store ctx
#pragma unroll
  for (int i = 0; i < 2; ++i)
#pragma unroll
    for (int r = 0; r < 4; ++r) {
      float lv = __shfl(l_col[i], quad * 4 + r, 64);
      float inv_l = 1.0f / lv;
      int row = wq_abs + i * 16 + quad * 4 + r;
#pragma unroll
      for (int jd = 0; jd < 8; ++jd) {
        int col = jd * 16 + l16;
        Oh[(size_t)row * D_ + col] = (bf16)(o_acc[i][jd][r] * inv_l);
      }
    }
}

// ---------------------------------------------------------------------------
extern "C" void kernel_launch(void* const* d_in, const int* in_sizes, int n_in,
                              void* d_out, int out_size, void* d_ws, size_t ws_size,
                              hipStream_t stream) {
  const float* x    = (const float*)d_in[0];
  const float* Wq   = (const float*)d_in[1];
  const float* Wk   = (const float*)d_in[2];
  const float* Wv   = (const float*)d_in[3];
  const float* Wo   = (const float*)d_in[4];
  const float* cosT = (const float*)d_in[5];
  const float* sinT = (const float*)d_in[6];
  float* out = (float*)d_out;

  const size_t NE = (size_t)B_ * S_ * D_;   // 8,388,608
  const size_t WE = (size_t)D_ * D_;        // 4,194,304
  bf16* Qb    = (bf16*)d_ws;                // ws: Q|K|V|C|Wslot = 72 MB
  bf16* Kb    = Qb + NE;
  bf16* Vb    = Kb + NE;
  bf16* Cb    = Vb + NE;                    // bf16(x) -> later Vt
  bf16* Wslot = Cb + NE;

  const int M = B_ * S_;
  dim3 gg(D_ / GTN, M / GTM);               // (16, 32)
  const int cvtX = (int)(NE / 1024);
  const int cvtW = (int)(WE / 1024);

  cvt_f32_bf16<<<cvtX, 256, 0, stream>>>(x, Cb);
  cvt_f32_bf16<<<cvtW, 256, 0, stream>>>(Wq, Wslot);
  gemm_xwt<bf16><<<gg, 256, 0, stream>>>(Cb, Wslot, Qb, M, D_, D_);
  cvt_f32_bf16<<<cvtW, 256, 0, stream>>>(Wk, Wslot);
  gemm_xwt<bf16><<<gg, 256, 0, stream>>>(Cb, Wslot, Kb, M, D_, D_);
  cvt_f32_bf16<<<cvtW, 256, 0, stream>>>(Wv, Wslot);
  gemm_xwt<bf16><<<gg, 256, 0, stream>>>(Cb, Wslot, Vb, M, D_, D_);
  rope_qk<<<(B_ * S_ * H_ * 64) / 256, 256, 0, stream>>>(Qb, Kb, cosT, sinT);
  // x (Cb) dead: transpose V into Cb, ctx goes into Vb.
  transpose_v<<<dim3(32, 2, 32), 256, 0, stream>>>(Vb, Cb);
  attn_fwd<<<512, 256, 0, stream>>>(Qb, Kb, Cb, Vb);
  cvt_f32_bf16<<<cvtW, 256, 0, stream>>>(Wo, Wslot);
  gemm_xwt<float><<<gg, 256, 0, stream>>>(Vb, Wslot, out, M, D_, D_);
}